// Round 3
// baseline (204.289 us; speedup 1.0000x reference)
//
#include <hip/hip_runtime.h>
#include <float.h>
#include <math.h>

#define SCORE_TH 0.05f
#define IOU_TH   0.5f
#define MAXD     100
#define CAP      512       // per-class candidate buffer (E[n]=200, sigma=14 -> 22 sigma margin)
#define HI_TH    0.996f    // P(uniform^4 > 0.996) ~ 1.0e-3 -> ~200 cand/class
#define SWALK    192       // sorted prefix examined by the walk (need ~110 to keep 100)

// ---------------- K1: decode + clip + areas ----------------
__global__ void k_decode(const float4* __restrict__ anch,
                         const float4* __restrict__ reg,
                         const int* __restrict__ ph, const int* __restrict__ pw,
                         float4* __restrict__ boxes, float* __restrict__ areas, int A)
{
    int a = blockIdx.x * blockDim.x + threadIdx.x;
    if (a >= A) return;
    float4 an = anch[a];
    float4 r  = reg[a];
    float W = (float)(*pw), H = (float)(*ph);
    float wa = an.z - an.x, ha = an.w - an.y;
    float cxa = an.x + 0.5f * wa, cya = an.y + 0.5f * ha;
    float cx = cxa + r.x * 0.1f * wa;
    float cy = cya + r.y * 0.1f * ha;
    float w  = expf(r.z * 0.2f) * wa;
    float h  = expf(r.w * 0.2f) * ha;
    float x1 = cx - 0.5f * w, y1 = cy - 0.5f * h;
    float x2 = cx + 0.5f * w, y2 = cy + 0.5f * h;
    x1 = fminf(fmaxf(x1, 0.f), W);
    y1 = fminf(fmaxf(y1, 0.f), H);
    x2 = fminf(fmaxf(x2, 0.f), W);
    y2 = fminf(fmaxf(y2, 0.f), H);
    boxes[a] = make_float4(x1, y1, x2, y2);
    areas[a] = (x2 - x1) * (y2 - y1);
}

// ---------------- K2: per-class candidate compaction (dominant kernel: 64MB scan) ----------------
__global__ void k_compact(const float4* __restrict__ cls4, float2* __restrict__ cand,
                          int* __restrict__ cnt, int* __restrict__ loflag,
                          int A, int C, long long total4)
{
    __shared__ unsigned char lflag[256];   // C <= 256 assumed (C=80 here)
    for (int i = threadIdx.x; i < C; i += blockDim.x) lflag[i] = 0;
    __syncthreads();
    long long i4 = (long long)blockIdx.x * blockDim.x + threadIdx.x;
    if (i4 < total4) {
        float4 v = cls4[i4];
        float s[4] = {v.x, v.y, v.z, v.w};
        long long base = i4 * 4;
        int c = (int)(base % C);
        int a = (int)(base / C);
        #pragma unroll
        for (int j = 0; j < 4; j++) {
            float sc = s[j];
            if (sc > HI_TH) {
                int pos = atomicAdd(&cnt[c], 1);
                if (pos < CAP) cand[(size_t)c * CAP + pos] = make_float2(sc, __int_as_float(a));
            } else if (sc > SCORE_TH) {
                lflag[c] = 1;               // racy idempotent byte write: fine
            }
            c++; if (c == C) { c = 0; a++; }
        }
    }
    __syncthreads();
    for (int i = threadIdx.x; i < C; i += blockDim.x)
        if (lflag[i]) loflag[i] = 1;        // plain store of 1: idempotent
}

// ---------------- K3: sort-then-walk exact NMS per class ----------------
// Greedy NMS == walk candidates in descending (score, -anchor) order, keep unless
// suppressed by an already-kept box. Sort once (bitonic 512), walk top SWALK with
// kept boxes in wave-0 registers (no barriers in the walk). Any shortfall -> K4.
__global__ __launch_bounds__(256)
void k_nms(const float4* __restrict__ boxes, const float* __restrict__ areas,
           const float2* __restrict__ cand, const int* __restrict__ cnt,
           const int* __restrict__ loflag, int* __restrict__ incomp,
           float* __restrict__ out, int C)
{
    int c = blockIdx.x;
    __shared__ unsigned long long keys[CAP];       // ascending key = best first
    __shared__ float bx1[SWALK], by1[SWALK], bx2[SWALK], by2[SWALK], sar[SWALK];
    __shared__ int   kidx[MAXD];
    __shared__ int   kept_s;

    int n_raw = cnt[c];
    if (n_raw > CAP) {                   // lost candidates -> exact fallback (uniform early return)
        if (threadIdx.x == 0) incomp[c] = 1;
        return;
    }
    int n = n_raw;

    // load + pack keys: ascending order == descending score, tie -> ascending anchor id
    for (int i = threadIdx.x; i < CAP; i += blockDim.x) {
        if (i < n) {
            float2 e = cand[(size_t)c * CAP + i];
            unsigned sbits = __float_as_uint(e.x);          // score > 0 -> bits monotone
            unsigned aid   = (unsigned)__float_as_int(e.y); // anchor id
            keys[i] = ((unsigned long long)(~sbits) << 32) | (unsigned long long)aid;
        } else {
            keys[i] = 0xFFFFFFFFFFFFFFFFull;                // pad sorts last
        }
    }
    __syncthreads();

    // canonical ascending bitonic sort, 512 elems, 256 threads
    for (int k = 2; k <= CAP; k <<= 1) {
        for (int j = k >> 1; j > 0; j >>= 1) {
            for (int i = threadIdx.x; i < CAP; i += blockDim.x) {
                int ixj = i ^ j;
                if (ixj > i) {
                    unsigned long long a = keys[i], b = keys[ixj];
                    bool sw = ((i & k) == 0) ? (a > b) : (a < b);
                    if (sw) { keys[i] = b; keys[ixj] = a; }
                }
            }
            __syncthreads();
        }
    }

    // stage boxes of the sorted prefix
    int nS = n < SWALK ? n : SWALK;
    for (int i = threadIdx.x; i < nS; i += blockDim.x) {
        unsigned aid = (unsigned)keys[i];
        float4 b = boxes[aid];
        bx1[i] = b.x; by1[i] = b.y; bx2[i] = b.z; by2[i] = b.w;
        sar[i] = areas[aid];
    }
    __syncthreads();

    // single-wave sequential walk; kept boxes live in registers (2 slots/lane)
    if (threadIdx.x < 64) {
        int t = threadIdx.x;
        int kept = 0;
        float a0x1 = 0.f, a0y1 = 0.f, a0x2 = 0.f, a0y2 = 0.f, a0a = 0.f;  // kept slot t
        float a1x1 = 0.f, a1y1 = 0.f, a1x2 = 0.f, a1y2 = 0.f, a1a = 0.f;  // kept slot 64+t
        for (int k = 0; k < nS && kept < MAXD; ++k) {
            float cx1 = bx1[k], cy1 = by1[k], cx2 = bx2[k], cy2 = by2[k], ca = sar[k]; // LDS broadcast
            bool supp = false;
            if (t < kept) {
                float xx1 = fmaxf(cx1, a0x1), yy1 = fmaxf(cy1, a0y1);
                float xx2 = fminf(cx2, a0x2), yy2 = fminf(cy2, a0y2);
                float inter = fmaxf(xx2 - xx1, 0.f) * fmaxf(yy2 - yy1, 0.f);
                float iou = inter / (ca + a0a - inter);     // NaN -> false, matches JAX
                supp = iou > IOU_TH;
            }
            if (64 + t < kept) {
                float xx1 = fmaxf(cx1, a1x1), yy1 = fmaxf(cy1, a1y1);
                float xx2 = fminf(cx2, a1x2), yy2 = fminf(cy2, a1y2);
                float inter = fmaxf(xx2 - xx1, 0.f) * fmaxf(yy2 - yy1, 0.f);
                float iou = inter / (ca + a1a - inter);
                supp = supp || (iou > IOU_TH);
            }
            if (!__any(supp)) {
                if (kept == t)            { a0x1 = cx1; a0y1 = cy1; a0x2 = cx2; a0y2 = cy2; a0a = ca; }
                else if (kept == 64 + t)  { a1x1 = cx1; a1y1 = cy1; a1x2 = cx2; a1y2 = cy2; a1a = ca; }
                if (t == 0) kidx[kept] = k;
                ++kept;
            }
        }
        if (t == 0) kept_s = kept;
    }
    __syncthreads();

    int kept = kept_s;
    if (kept < MAXD && (n > nS || loflag[c] != 0)) {   // unexamined candidates may exist
        if (threadIdx.x == 0) incomp[c] = 1;           // -> exact fallback owns this class
        return;
    }

    int total = C * MAXD;
    int base = c * MAXD;
    for (int m = threadIdx.x; m < kept; m += blockDim.x) {
        int k = kidx[m];
        unsigned long long key = keys[k];
        float sc = __uint_as_float(~(unsigned)(key >> 32));
        out[base + m] = sc;
        out[total + base + m] = (float)c;
        float* ob = out + 2 * (size_t)total + (size_t)(base + m) * 4;
        ob[0] = bx1[k]; ob[1] = by1[k]; ob[2] = bx2[k]; ob[3] = by2[k];
    }
    for (int m = kept + threadIdx.x; m < MAXD; m += blockDim.x) {
        out[base + m] = 0.f;
        out[total + base + m] = -1.f;
        float* ob = out + 2 * (size_t)total + (size_t)(base + m) * 4;
        ob[0] = 0.f; ob[1] = 0.f; ob[2] = 0.f; ob[3] = 0.f;
    }
}

// ---------------- K4: exact fallback (lazy sorted-order walk over all A; statistically never fires) ----------------
__global__ __launch_bounds__(256)
void k_fallback(const float* __restrict__ cls,
                const float4* __restrict__ boxes, const float* __restrict__ areas,
                const int* __restrict__ incomp, float* __restrict__ out,
                int A, int C)
{
    int c = blockIdx.x;
    if (!incomp[c]) return;
    __shared__ float kx1[MAXD], ky1[MAXD], kx2[MAXD], ky2[MAXD], kar[MAXD];
    __shared__ float rs[4]; __shared__ int ra[4];
    __shared__ float cs; __shared__ int caid; __shared__ int have; __shared__ int suppflag;
    int lane = threadIdx.x & 63, wid = threadIdx.x >> 6;
    float s_last = FLT_MAX; int a_last = -1;
    int kept = 0;
    int total = C * MAXD;
    for (long long guard = 0; guard <= (long long)A && kept < MAXD; guard++) {
        // next candidate strictly after (s_last, a_last) in descending (score, -idx) order
        float bs = -1.f; int ba = 0x7fffffff;
        for (int a = threadIdx.x; a < A; a += blockDim.x) {
            float s = cls[(size_t)a * C + c];
            if (s <= SCORE_TH) continue;
            if (s > s_last || (s == s_last && a <= a_last)) continue;  // already examined
            if (s > bs || (s == bs && a < ba)) { bs = s; ba = a; }
        }
        for (int off = 32; off >= 1; off >>= 1) {
            float s2 = __shfl_down(bs, off);
            int a2 = __shfl_down(ba, off);
            if (s2 > bs || (s2 == bs && a2 < ba)) { bs = s2; ba = a2; }
        }
        if (lane == 0) { rs[wid] = bs; ra[wid] = ba; }
        __syncthreads();
        if (threadIdx.x == 0) {
            float fs = rs[0]; int fa = ra[0];
            for (int w = 1; w < 4; w++)
                if (rs[w] > fs || (rs[w] == fs && ra[w] < fa)) { fs = rs[w]; fa = ra[w]; }
            cs = fs; caid = fa; have = (fs > 0.f) ? 1 : 0;
        }
        __syncthreads();
        if (!have) break;
        float s_c = cs; int a_c = caid;
        s_last = s_c; a_last = a_c;
        float4 b = boxes[a_c]; float ar = areas[a_c];
        if (threadIdx.x == 0) suppflag = 0;
        __syncthreads();
        for (int k = threadIdx.x; k < kept; k += blockDim.x) {
            float xx1 = fmaxf(b.x, kx1[k]);
            float yy1 = fmaxf(b.y, ky1[k]);
            float xx2 = fminf(b.z, kx2[k]);
            float yy2 = fminf(b.w, ky2[k]);
            float inter = fmaxf(xx2 - xx1, 0.f) * fmaxf(yy2 - yy1, 0.f);
            float iou = inter / (ar + kar[k] - inter);
            if (iou > IOU_TH) suppflag = 1;  // racy idempotent
        }
        __syncthreads();
        if (!suppflag) {
            if (threadIdx.x == 0) {
                kx1[kept] = b.x; ky1[kept] = b.y; kx2[kept] = b.z; ky2[kept] = b.w; kar[kept] = ar;
                int slot = c * MAXD + kept;
                out[slot] = s_c;
                out[total + slot] = (float)c;
                float* ob = out + 2 * (size_t)total + (size_t)slot * 4;
                ob[0] = b.x; ob[1] = b.y; ob[2] = b.z; ob[3] = b.w;
            }
            kept++;
        }
        __syncthreads();
    }
    for (int k = kept + threadIdx.x; k < MAXD; k += blockDim.x) {
        int slot = c * MAXD + k;
        out[slot] = 0.f;
        out[total + slot] = -1.f;
        float* ob = out + 2 * (size_t)total + (size_t)slot * 4;
        ob[0] = 0.f; ob[1] = 0.f; ob[2] = 0.f; ob[3] = 0.f;
    }
}

extern "C" void kernel_launch(void* const* d_in, const int* in_sizes, int n_in,
                              void* d_out, int out_size, void* d_ws, size_t ws_size,
                              hipStream_t stream)
{
    const float*  cls  = (const float*)d_in[0];
    const float4* reg  = (const float4*)d_in[1];
    const float4* anch = (const float4*)d_in[2];
    const int*    ph   = (const int*)d_in[3];
    const int*    pw   = (const int*)d_in[4];
    int A = in_sizes[1] / 4;
    int C = in_sizes[0] / A;
    float* out = (float*)d_out;

    char* ws = (char*)d_ws;
    float4* boxes = (float4*)ws;                       // A * 16B
    float*  areas = (float*)(boxes + A);               // A * 4B
    float2* cand  = (float2*)(areas + A);              // C*CAP * 8B
    int* ctrl   = (int*)(cand + (size_t)C * CAP);      // cnt[C] | loflag[C] | incomp[C]
    int* cnt    = ctrl;
    int* loflag = ctrl + C;
    int* incomp = ctrl + 2 * C;

    hipMemsetAsync(ctrl, 0, 3 * C * sizeof(int), stream);

    k_decode<<<(A + 255) / 256, 256, 0, stream>>>(anch, reg, ph, pw, boxes, areas, A);

    long long total4 = (long long)A * C / 4;
    int blocks2 = (int)((total4 + 255) / 256);
    k_compact<<<blocks2, 256, 0, stream>>>((const float4*)cls, cand, cnt, loflag, A, C, total4);

    k_nms<<<C, 256, 0, stream>>>(boxes, areas, cand, cnt, loflag, incomp, out, C);
    k_fallback<<<C, 256, 0, stream>>>(cls, boxes, areas, incomp, out, A, C);
}

// Round 8
// 144.687 us; speedup vs baseline: 1.4119x; 1.4119x over previous
//
#include <hip/hip_runtime.h>
#include <float.h>
#include <math.h>

#define SCORE_TH 0.05f
#define IOU_TH   0.5f
#define MAXD     100
#define CAP      512       // per-class candidate buffer (E[n]=200, sigma=14 -> 22 sigma margin)
#define HI_TH    0.996f    // P(uniform^4 > 0.996) ~ 1.0e-3 -> ~200 cand/class
#define SWALK    192       // sorted prefix examined by the walk (need ~110 to keep 100)
#define CNT_STRIDE 16      // pad class counters to one 64B line each (atomic line-parallelism)

// Inline RetinaNet decode + clip (identical arithmetic to the previously verified k_decode)
__device__ __forceinline__ float4 decode_box(float4 an, float4 r, float W, float H)
{
    float wa = an.z - an.x, ha = an.w - an.y;
    float cxa = an.x + 0.5f * wa, cya = an.y + 0.5f * ha;
    float cx = cxa + r.x * 0.1f * wa;
    float cy = cya + r.y * 0.1f * ha;
    float w  = expf(r.z * 0.2f) * wa;
    float h  = expf(r.w * 0.2f) * ha;
    float x1 = cx - 0.5f * w, y1 = cy - 0.5f * h;
    float x2 = cx + 0.5f * w, y2 = cy + 0.5f * h;
    x1 = fminf(fmaxf(x1, 0.f), W);
    y1 = fminf(fmaxf(y1, 0.f), H);
    x2 = fminf(fmaxf(x2, 0.f), W);
    y2 = fminf(fmaxf(y2, 0.f), H);
    return make_float4(x1, y1, x2, y2);
}

// ---------------- K2: grid-stride candidate compaction (dominant kernel: 64MB scan) ----------------
// CC>0: compile-time class count (strength-reduced div/mod). CC==0: generic runtime path.
template<int CC>
__global__ __launch_bounds__(256)
void k_compact(const float4* __restrict__ cls4, float2* __restrict__ cand,
               int* __restrict__ cnt, int* __restrict__ loflag,
               int C_rt, int total4)
{
    const int C = CC ? CC : C_rt;
    __shared__ unsigned char lflag[256];   // C <= 256 assumed (C=80 here)
    for (int i = threadIdx.x; i < C; i += blockDim.x) lflag[i] = 0;
    __syncthreads();

    const int gstride = gridDim.x * blockDim.x;
    const int gtid = blockIdx.x * blockDim.x + threadIdx.x;

    for (int j0 = gtid; j0 < total4; j0 += 4 * gstride) {
        int j1 = j0 + gstride, j2 = j0 + 2 * gstride, j3 = j0 + 3 * gstride;
        bool ok1 = j1 < total4, ok2 = j2 < total4, ok3 = j3 < total4;
        // 4 independent coalesced 16B loads in flight
        float4 v0 = cls4[j0];
        float4 v1 = ok1 ? cls4[j1] : make_float4(0.f, 0.f, 0.f, 0.f);
        float4 v2 = ok2 ? cls4[j2] : make_float4(0.f, 0.f, 0.f, 0.f);
        float4 v3 = ok3 ? cls4[j3] : make_float4(0.f, 0.f, 0.f, 0.f);

        #pragma unroll
        for (int w = 0; w < 4; w++) {
            float4 v = (w == 0) ? v0 : (w == 1) ? v1 : (w == 2) ? v2 : v3;
            if (w == 1 && !ok1) break;
            if (w == 2 && !ok2) break;
            if (w == 3 && !ok3) break;
            unsigned b = (unsigned)(j0 + w * gstride) * 4u;   // flat element index (<2^31)
            int c = (int)(b % (unsigned)C);
            int a = (int)(b / (unsigned)C);
            float s[4] = {v.x, v.y, v.z, v.w};
            #pragma unroll
            for (int j = 0; j < 4; j++) {
                float sc = s[j];
                if (sc > HI_TH) {
                    int pos = atomicAdd(&cnt[c * CNT_STRIDE], 1);
                    if (pos < CAP) cand[(size_t)c * CAP + pos] = make_float2(sc, __int_as_float(a));
                } else if (sc > SCORE_TH) {
                    lflag[c] = 1;           // racy idempotent byte write: fine
                }
                c++; if (c == C) { c = 0; a++; }
            }
        }
    }
    __syncthreads();
    for (int i = threadIdx.x; i < C; i += blockDim.x)
        if (lflag[i]) loflag[i] = 1;        // plain store of 1: idempotent
}

// ---------------- K3: sort-then-walk exact NMS per class ----------------
// Greedy NMS == walk candidates in descending (score, -anchor) order, keep unless
// suppressed by an already-kept box. Sort once (adaptive bitonic 256/512), decode
// candidate boxes inline while staging, walk top SWALK with kept boxes in wave-0
// registers (no barriers in the walk). Shortfall -> K4.
__global__ __launch_bounds__(256)
void k_nms(const float4* __restrict__ anch, const float4* __restrict__ reg,
           const int* __restrict__ ph, const int* __restrict__ pw,
           const float2* __restrict__ cand, const int* __restrict__ cnt,
           const int* __restrict__ loflag, int* __restrict__ incomp,
           float* __restrict__ out, int C)
{
    int c = blockIdx.x;
    __shared__ unsigned long long keys[CAP];       // ascending key = best first
    __shared__ float bx1[SWALK], by1[SWALK], bx2[SWALK], by2[SWALK], sar[SWALK];
    __shared__ int   kidx[MAXD];
    __shared__ int   kept_s;

    int n_raw = cnt[c * CNT_STRIDE];
    if (n_raw > CAP) {                   // lost candidates -> exact fallback (uniform early return)
        if (threadIdx.x == 0) incomp[c] = 1;
        return;
    }
    int n = n_raw;

    // load + pack keys: ascending order == descending score, tie -> ascending anchor id
    for (int i = threadIdx.x; i < CAP; i += blockDim.x) {
        if (i < n) {
            float2 e = cand[(size_t)c * CAP + i];
            unsigned sbits = __float_as_uint(e.x);          // score > 0 -> bits monotone
            unsigned aid   = (unsigned)__float_as_int(e.y); // anchor id
            keys[i] = ((unsigned long long)(~sbits) << 32) | (unsigned long long)aid;
        } else {
            keys[i] = 0xFFFFFFFFFFFFFFFFull;                // pad sorts last
        }
    }
    __syncthreads();

    // adaptive ascending bitonic sort: 256-wide network when n fits (common case, 36
    // passes), else full 512 (45 passes). Walk only reads keys[0..min(n,SWALK)).
    const int SORTN = (n <= 256) ? 256 : CAP;
    for (int k = 2; k <= SORTN; k <<= 1) {
        for (int j = k >> 1; j > 0; j >>= 1) {
            for (int i = threadIdx.x; i < SORTN; i += blockDim.x) {
                int ixj = i ^ j;
                if (ixj > i) {
                    unsigned long long a = keys[i], b = keys[ixj];
                    bool sw = ((i & k) == 0) ? (a > b) : (a < b);
                    if (sw) { keys[i] = b; keys[ixj] = a; }
                }
            }
            __syncthreads();
        }
    }

    // stage sorted prefix: gather anchors+regression, decode inline (only ~nS anchors
    // ever need decoding -- saves the full-A decode kernel + 9.6MB of HBM traffic)
    float W = (float)(*pw), H = (float)(*ph);
    int nS = n < SWALK ? n : SWALK;
    for (int i = threadIdx.x; i < nS; i += blockDim.x) {
        unsigned aid = (unsigned)keys[i];
        float4 b = decode_box(anch[aid], reg[aid], W, H);
        bx1[i] = b.x; by1[i] = b.y; bx2[i] = b.z; by2[i] = b.w;
        sar[i] = (b.z - b.x) * (b.w - b.y);
    }
    __syncthreads();

    // single-wave sequential walk; kept boxes live in registers (2 slots/lane)
    if (threadIdx.x < 64) {
        int t = threadIdx.x;
        int kept = 0;
        float a0x1 = 0.f, a0y1 = 0.f, a0x2 = 0.f, a0y2 = 0.f, a0a = 0.f;  // kept slot t
        float a1x1 = 0.f, a1y1 = 0.f, a1x2 = 0.f, a1y2 = 0.f, a1a = 0.f;  // kept slot 64+t
        for (int k = 0; k < nS && kept < MAXD; ++k) {
            float cx1 = bx1[k], cy1 = by1[k], cx2 = bx2[k], cy2 = by2[k], ca = sar[k]; // LDS broadcast
            bool supp = false;
            if (t < kept) {
                float xx1 = fmaxf(cx1, a0x1), yy1 = fmaxf(cy1, a0y1);
                float xx2 = fminf(cx2, a0x2), yy2 = fminf(cy2, a0y2);
                float inter = fmaxf(xx2 - xx1, 0.f) * fmaxf(yy2 - yy1, 0.f);
                float iou = inter / (ca + a0a - inter);     // NaN -> false, matches JAX
                supp = iou > IOU_TH;
            }
            if (64 + t < kept) {
                float xx1 = fmaxf(cx1, a1x1), yy1 = fmaxf(cy1, a1y1);
                float xx2 = fminf(cx2, a1x2), yy2 = fminf(cy2, a1y2);
                float inter = fmaxf(xx2 - xx1, 0.f) * fmaxf(yy2 - yy1, 0.f);
                float iou = inter / (ca + a1a - inter);
                supp = supp || (iou > IOU_TH);
            }
            if (!__any(supp)) {
                if (kept == t)            { a0x1 = cx1; a0y1 = cy1; a0x2 = cx2; a0y2 = cy2; a0a = ca; }
                else if (kept == 64 + t)  { a1x1 = cx1; a1y1 = cy1; a1x2 = cx2; a1y2 = cy2; a1a = ca; }
                if (t == 0) kidx[kept] = k;
                ++kept;
            }
        }
        if (t == 0) kept_s = kept;
    }
    __syncthreads();

    int kept = kept_s;
    if (kept < MAXD && (n > nS || loflag[c] != 0)) {   // unexamined candidates may exist
        if (threadIdx.x == 0) incomp[c] = 1;           // -> exact fallback owns this class
        return;
    }

    int total = C * MAXD;
    int base = c * MAXD;
    for (int m = threadIdx.x; m < kept; m += blockDim.x) {
        int k = kidx[m];
        unsigned long long key = keys[k];
        float sc = __uint_as_float(~(unsigned)(key >> 32));
        out[base + m] = sc;
        out[total + base + m] = (float)c;
        float* ob = out + 2 * (size_t)total + (size_t)(base + m) * 4;
        ob[0] = bx1[k]; ob[1] = by1[k]; ob[2] = bx2[k]; ob[3] = by2[k];
    }
    for (int m = kept + threadIdx.x; m < MAXD; m += blockDim.x) {
        out[base + m] = 0.f;
        out[total + base + m] = -1.f;
        float* ob = out + 2 * (size_t)total + (size_t)(base + m) * 4;
        ob[0] = 0.f; ob[1] = 0.f; ob[2] = 0.f; ob[3] = 0.f;
    }
}

// ---------------- K4: exact fallback (lazy sorted-order walk over all A; statistically never fires) ----------------
__global__ __launch_bounds__(256)
void k_fallback(const float* __restrict__ cls,
                const float4* __restrict__ anch, const float4* __restrict__ reg,
                const int* __restrict__ ph, const int* __restrict__ pw,
                const int* __restrict__ incomp, float* __restrict__ out,
                int A, int C)
{
    int c = blockIdx.x;
    if (!incomp[c]) return;
    __shared__ float kx1[MAXD], ky1[MAXD], kx2[MAXD], ky2[MAXD], kar[MAXD];
    __shared__ float rs[4]; __shared__ int ra[4];
    __shared__ float cs; __shared__ int caid; __shared__ int have; __shared__ int suppflag;
    int lane = threadIdx.x & 63, wid = threadIdx.x >> 6;
    float W = (float)(*pw), H = (float)(*ph);
    float s_last = FLT_MAX; int a_last = -1;
    int kept = 0;
    int total = C * MAXD;
    for (long long guard = 0; guard <= (long long)A && kept < MAXD; guard++) {
        // next candidate strictly after (s_last, a_last) in descending (score, -idx) order
        float bs = -1.f; int ba = 0x7fffffff;
        for (int a = threadIdx.x; a < A; a += blockDim.x) {
            float s = cls[(size_t)a * C + c];
            if (s <= SCORE_TH) continue;
            if (s > s_last || (s == s_last && a <= a_last)) continue;  // already examined
            if (s > bs || (s == bs && a < ba)) { bs = s; ba = a; }
        }
        for (int off = 32; off >= 1; off >>= 1) {
            float s2 = __shfl_down(bs, off);
            int a2 = __shfl_down(ba, off);
            if (s2 > bs || (s2 == bs && a2 < ba)) { bs = s2; ba = a2; }
        }
        if (lane == 0) { rs[wid] = bs; ra[wid] = ba; }
        __syncthreads();
        if (threadIdx.x == 0) {
            float fs = rs[0]; int fa = ra[0];
            for (int w = 1; w < 4; w++)
                if (rs[w] > fs || (rs[w] == fs && ra[w] < fa)) { fs = rs[w]; fa = ra[w]; }
            cs = fs; caid = fa; have = (fs > 0.f) ? 1 : 0;
        }
        __syncthreads();
        if (!have) break;
        float s_c = cs; int a_c = caid;
        s_last = s_c; a_last = a_c;
        float4 b = decode_box(anch[a_c], reg[a_c], W, H);   // inline decode (redundant per thread, cheap)
        float ar = (b.z - b.x) * (b.w - b.y);
        if (threadIdx.x == 0) suppflag = 0;
        __syncthreads();
        for (int k = threadIdx.x; k < kept; k += blockDim.x) {
            float xx1 = fmaxf(b.x, kx1[k]);
            float yy1 = fmaxf(b.y, ky1[k]);
            float xx2 = fminf(b.z, kx2[k]);
            float yy2 = fminf(b.w, ky2[k]);
            float inter = fmaxf(xx2 - xx1, 0.f) * fmaxf(yy2 - yy1, 0.f);
            float iou = inter / (ar + kar[k] - inter);
            if (iou > IOU_TH) suppflag = 1;  // racy idempotent
        }
        __syncthreads();
        if (!suppflag) {
            if (threadIdx.x == 0) {
                kx1[kept] = b.x; ky1[kept] = b.y; kx2[kept] = b.z; ky2[kept] = b.w; kar[kept] = ar;
                int slot = c * MAXD + kept;
                out[slot] = s_c;
                out[total + slot] = (float)c;
                float* ob = out + 2 * (size_t)total + (size_t)slot * 4;
                ob[0] = b.x; ob[1] = b.y; ob[2] = b.z; ob[3] = b.w;
            }
            kept++;
        }
        __syncthreads();
    }
    for (int k = kept + threadIdx.x; k < MAXD; k += blockDim.x) {
        int slot = c * MAXD + k;
        out[slot] = 0.f;
        out[total + slot] = -1.f;
        float* ob = out + 2 * (size_t)total + (size_t)slot * 4;
        ob[0] = 0.f; ob[1] = 0.f; ob[2] = 0.f; ob[3] = 0.f;
    }
}

extern "C" void kernel_launch(void* const* d_in, const int* in_sizes, int n_in,
                              void* d_out, int out_size, void* d_ws, size_t ws_size,
                              hipStream_t stream)
{
    const float*  cls  = (const float*)d_in[0];
    const float4* reg  = (const float4*)d_in[1];
    const float4* anch = (const float4*)d_in[2];
    const int*    ph   = (const int*)d_in[3];
    const int*    pw   = (const int*)d_in[4];
    int A = in_sizes[1] / 4;
    int C = in_sizes[0] / A;
    float* out = (float*)d_out;

    char* ws = (char*)d_ws;
    float2* cand = (float2*)ws;                        // C*CAP * 8B
    int* ctrl   = (int*)(cand + (size_t)C * CAP);      // cnt_pad[C*16] | loflag[C] | incomp[C]
    int* cnt    = ctrl;                                // strided by CNT_STRIDE
    int* loflag = ctrl + C * CNT_STRIDE;
    int* incomp = loflag + C;

    hipMemsetAsync(ctrl, 0, (C * CNT_STRIDE + 2 * C) * sizeof(int), stream);

    int total4 = (int)((long long)A * C / 4);
    int blocks2 = (total4 + 255) / 256;
    if (blocks2 > 2048) blocks2 = 2048;
    if (C == 80 && (long long)A * C < (1LL << 31))
        k_compact<80><<<blocks2, 256, 0, stream>>>((const float4*)cls, cand, cnt, loflag, C, total4);
    else
        k_compact<0><<<blocks2, 256, 0, stream>>>((const float4*)cls, cand, cnt, loflag, C, total4);

    k_nms<<<C, 256, 0, stream>>>(anch, reg, ph, pw, cand, cnt, loflag, incomp, out, C);
    k_fallback<<<C, 256, 0, stream>>>(cls, anch, reg, ph, pw, incomp, out, A, C);
}